// Round 1
// baseline (210.641 us; speedup 1.0000x reference)
//
#include <hip/hip_runtime.h>
#include <math.h>

typedef __attribute__((ext_vector_type(8))) short bf16x8;
typedef __attribute__((ext_vector_type(16))) float f32x16;
typedef __attribute__((ext_vector_type(4))) float vf4;
typedef __attribute__((ext_vector_type(4))) unsigned int u32x4;

__device__ __forceinline__ float wave_reduce(float v) {
#pragma unroll
    for (int off = 32; off > 0; off >>= 1) v += __shfl_down(v, off, 64);
    return v;
}

// truncation fp32->bf16 pack: two floats -> one dword (hi16(f1)<<16 | hi16(f0)).
__device__ __forceinline__ unsigned int pk_trunc(float f0, float f1) {
    unsigned u0 = __float_as_uint(f0), u1 = __float_as_uint(f1);
    return (u1 & 0xFFFF0000u) | (u0 >> 16);
}

// Fused angular+center.
// Ang: one 32x32 gram tile per wave via v_mfma_f32_32x32x16_bf16 (1024 tiles,
// on the first 256 blocks). fp32 centers converted in-flight (truncation);
// row norms in-register.
// Center: grid-stride feat stream.
// R10: grid 2048 -> 8192 blocks (4x oversubscription). With an
// exactly-resident 2048-block grid the 256 ang blocks finish their center
// share ~5us after everyone else on their CU and nothing can backfill
// (exposed tail). Oversubscribing lets the HW dispatcher rebalance: CUs
// carrying an ang block just consume fewer queued center blocks.
__global__ __launch_bounds__(256) void fused_kernel(const int* __restrict__ y,
                                                    const vf4* __restrict__ feat4,
                                                    const vf4* __restrict__ cent4,
                                                    float* __restrict__ partials,
                                                    int n4, int d4, float cen_scale,
                                                    int C, int ntile32, int steps16,
                                                    float ct, float ang_scale) {
    const int bid = blockIdx.x;
    const int lane = threadIdx.x & 63;
    const int wid = threadIdx.x >> 6;
    __shared__ float sm[4];

    float partial = 0.f;

    // ---------------- angular: one 32x32 tile per wave ----------------
    const int t = bid * 4 + wid;            // global wave id == tile id
    const int ntile2 = ntile32 * ntile32;
    if (t < ntile2) {
        const int ti = t / ntile32;
        const int tj = t - ti * ntile32;
        const int m = lane & 31;            // A/B row within panel
        const int half = lane >> 5;         // k-half selector
        const int ra = ti * 32 + m;
        const int rb = tj * 32 + m;
        const bool va = ra < C;
        const bool vb = rb < C;
        const vf4* aptr = cent4 + (size_t)ra * d4 + half * 2;
        const vf4* bptr = cent4 + (size_t)rb * d4 + half * 2;
        f32x16 acc;
#pragma unroll
        for (int k = 0; k < 16; ++k) acc[k] = 0.f;
        float sa = 0.f, sb = 0.f;
#pragma unroll 4
        for (int st = 0; st < steps16; ++st) {
            vf4 a0 = {0.f, 0.f, 0.f, 0.f}, a1 = a0, b0 = a0, b1 = a0;
            if (va) { a0 = aptr[st * 4]; a1 = aptr[st * 4 + 1]; }
            if (vb) { b0 = bptr[st * 4]; b1 = bptr[st * 4 + 1]; }
            sa += a0.x * a0.x + a0.y * a0.y + a0.z * a0.z + a0.w * a0.w
                + a1.x * a1.x + a1.y * a1.y + a1.z * a1.z + a1.w * a1.w;
            sb += b0.x * b0.x + b0.y * b0.y + b0.z * b0.z + b0.w * b0.w
                + b1.x * b1.x + b1.y * b1.y + b1.z * b1.z + b1.w * b1.w;
            u32x4 ap, bp;
            ap.x = pk_trunc(a0.x, a0.y); ap.y = pk_trunc(a0.z, a0.w);
            ap.z = pk_trunc(a1.x, a1.y); ap.w = pk_trunc(a1.z, a1.w);
            bp.x = pk_trunc(b0.x, b0.y); bp.y = pk_trunc(b0.z, b0.w);
            bp.z = pk_trunc(b1.x, b1.y); bp.w = pk_trunc(b1.z, b1.w);
            bf16x8 af = __builtin_bit_cast(bf16x8, ap);
            bf16x8 bf = __builtin_bit_cast(bf16x8, bp);
            acc = __builtin_amdgcn_mfma_f32_32x32x16_bf16(af, bf, acc, 0, 0, 0);
        }
        // combine the two k-halves of each row norm: lanes l and l^32 share row l&31
        sa += __shfl_xor(sa, 32, 64);
        sb += __shfl_xor(sb, 32, 64);
        // C/D layout (measured m74/m101): col = lane&31, row = (reg&3)+8*(reg>>2)+4*half
        const int gj = tj * 32 + m;
        const float dj = sb;                // norm of B row gj (col of this lane)
        float local = 0.f;
#pragma unroll
        for (int reg = 0; reg < 16; ++reg) {
            const int r = (reg & 3) + 8 * (reg >> 2) + 4 * half;
            const int gi = ti * 32 + r;
            const float di = __shfl(sa, r, 64);   // lane r holds norm of A row r
            if (gi < C && gj < C && gi != gj) {
                float sim = acc[reg] * rsqrtf(di * dj);
                float dlt = sim - ct;
                local += dlt * dlt;
            }
        }
        partial = local * ang_scale;
    }

    // ---------------- center: grid-stride over float4 elements of feat ----------------
    {
        const int stride = gridDim.x * 256;
        float cs = 0.f;
        int i = bid * 256 + threadIdx.x;
        if ((stride % d4) == 0) {
            if (i < n4) {
                int row = i / d4;
                const int col = i - row * d4;
                const int rstep = stride / d4;
                for (; i < n4; i += stride, row += rstep) {
                    const int cls = y[row];
                    vf4 f = __builtin_nontemporal_load(feat4 + i);
                    vf4 c = cent4[(size_t)cls * d4 + col];
                    float dx = f.x - c.x, dy = f.y - c.y, dz = f.z - c.z, dw = f.w - c.w;
                    cs += dx * dx + dy * dy + dz * dz + dw * dw;
                }
            }
        } else {
            for (; i < n4; i += stride) {
                int row = i / d4;
                int col = i - row * d4;
                const int cls = y[row];
                vf4 f = __builtin_nontemporal_load(feat4 + i);
                vf4 c = cent4[(size_t)cls * d4 + col];
                float dx = f.x - c.x, dy = f.y - c.y, dz = f.z - c.z, dw = f.w - c.w;
                cs += dx * dx + dy * dy + dz * dz + dw * dw;
            }
        }
        partial += cs * cen_scale;
    }

    // block reduce -> plain store to partials[bid] (no atomics anywhere)
    float r = wave_reduce(partial);
    if (lane == 0) sm[wid] = r;
    __syncthreads();
    if (threadIdx.x == 0) {
        partials[bid] = sm[0] + sm[1] + sm[2] + sm[3];
    }
}

// Kernel 2: single block reduces nb partials -> out[0] (plain store).
__global__ __launch_bounds__(256) void reduce_kernel(const float* __restrict__ partials,
                                                     float* __restrict__ out, int nb) {
    __shared__ float sm[4];
    const int lane = threadIdx.x & 63;
    const int wid = threadIdx.x >> 6;
    float s = 0.f;
    for (int i = threadIdx.x; i < nb; i += 256) s += partials[i];
    s = wave_reduce(s);
    if (lane == 0) sm[wid] = s;
    __syncthreads();
    if (threadIdx.x == 0) out[0] = sm[0] + sm[1] + sm[2] + sm[3];
}

extern "C" void kernel_launch(void* const* d_in, const int* in_sizes, int n_in,
                              void* d_out, int out_size, void* d_ws, size_t ws_size,
                              hipStream_t stream) {
    const int* y = (const int*)d_in[0];
    const float* feat = (const float*)d_in[1];
    const float* centers = (const float*)d_in[2];

    const int B = in_sizes[0];
    const int D = in_sizes[1] / B;
    const int C = in_sizes[2] / D;
    const int d4 = D / 4;
    const int ntile32 = (C + 31) / 32;

    // ct = costheta(C): static recurrence in double, matches Python reference.
    const int nd = C - 1;
    double r = 0.0;
    if (nd >= 2) {
        r = 0.5;
        for (int i = 3; i <= nd; ++i) r = 0.5 / sqrt(1.0 - r * r);
    }
    const float ct = (float)(2.0 * r * r - 1.0);

    const float cen_scale = (float)(0.5 / (double)B);
    const float ang_scale = (float)(1.0 / (0.5 * (double)C * (double)(C - 1)));

    float* partials = (float*)d_ws;
    const int nb = 8192;   // R10: 4x oversubscription (was 2048 exactly-resident).
                           // 32768 waves; 1024 ang tiles on blocks 0..255; 4 center
                           // iters/thread; HW dispatcher absorbs the ang-block tail.

    fused_kernel<<<nb, 256, 0, stream>>>(
        y, (const vf4*)feat, (const vf4*)centers, partials,
        B * d4, d4, cen_scale, C, ntile32, D / 16, ct, ang_scale);

    reduce_kernel<<<1, 256, 0, stream>>>(partials, (float*)d_out, nb);
}